// Round 1
// baseline (2531.189 us; speedup 1.0000x reference)
//
#include <hip/hip_runtime.h>
#include <cmath>

typedef unsigned short u16;
typedef __bf16 bf16x8 __attribute__((ext_vector_type(8)));
typedef float f32x4 __attribute__((ext_vector_type(4)));

#define SEQL 2048
#define NH 8
#define HD 64

static __device__ __forceinline__ u16 f2bf(float f) {
  union { float f; unsigned u; } v; v.f = f;
  unsigned u = v.u;
  unsigned r = (u + 0x7FFFu + ((u >> 16) & 1u)) >> 16;
  return (u16)r;
}
static __device__ __forceinline__ float bf2f(u16 h) {
  union { unsigned u; float f; } v; v.u = ((unsigned)h) << 16;
  return v.f;
}

// ---------------- fp32 -> bf16 convert (4 elems/thread) ----------------
__global__ __launch_bounds__(256) void cvt_kernel(const float* __restrict__ in,
                                                  u16* __restrict__ out, int n) {
  int i = (blockIdx.x * 256 + threadIdx.x) * 4;
  if (i < n) {
    float4 f = *(const float4*)(in + i);
    ushort4 o;
    o.x = f2bf(f.x); o.y = f2bf(f.y); o.z = f2bf(f.z); o.w = f2bf(f.w);
    *(ushort4*)(out + i) = o;
  }
}

// ---------------- rotary cos/sin table (fp64, matches numpy) ----------------
__global__ __launch_bounds__(256) void rot_table_kernel(float2* __restrict__ T) {
  int m = blockIdx.x, i = threadIdx.x;  // m: 0..2047, i: pair 0..255
  double theta = pow(10000.0, -2.0 * ((double)i - 1.0) / 512.0);
  double a = (double)m * theta;
  T[m * 256 + i] = make_float2((float)cos(a), (float)sin(a));
}

// ---------------- in-place rope on fused QKV (8192 x 1536 bf16) ----------------
__global__ __launch_bounds__(256) void rope_kernel(u16* __restrict__ QKV,
                                                   const float2* __restrict__ T) {
  int row = blockIdx.x;   // b*2048 + m
  int i = threadIdx.x;    // pair index
  int m = row & 2047;
  float2 cs = T[m * 256 + i];
  float c = cs.x, s = cs.y;
  size_t base = (size_t)row * 1536 + 2 * i;
  #pragma unroll
  for (int seg = 0; seg < 3; ++seg) {
    u16* p = QKV + base + seg * 512;
    ushort2 eo = *(ushort2*)p;
    float e = bf2f(eo.x), o = bf2f(eo.y);
    ushort2 w;
    w.x = f2bf(e * c + o * s);
    w.y = f2bf(-e * s + o * c);
    *(ushort2*)p = w;
  }
}

// ---------------- GEMM C = A @ B^T (+bias), MFMA 16x16x32 bf16 ----------------
// A: (M x K) bf16 row-major (lda), B: (N x K) bf16 row-major (ldb), K = 512.
// MODE 0: bf16 out at row*ldc+col.  MODE 1: bf16 out, bias, head-reordered
// (bh, m, hd).  MODE 2: fp32 out, bias.
template<int MODE>
__global__ __launch_bounds__(256) void gemm_bt(const u16* __restrict__ A, int lda,
                                               const u16* __restrict__ B, int ldb,
                                               const float* __restrict__ bias,
                                               void* __restrict__ Cv, int ldc) {
  __shared__ u16 As[128 * 80];   // 128 rows x 64 halfs, padded to 80 (160 B)
  __shared__ u16 Bs[128 * 80];
  int tid = threadIdx.x;
  int wid = tid >> 6, lane = tid & 63, quad = lane >> 4, l16 = lane & 15;
  int m0 = blockIdx.y * 128, n0 = blockIdx.x * 128;
  int wm = (wid >> 1) * 64, wn = (wid & 1) * 64;
  f32x4 acc[4][4] = {};
  for (int kb = 0; kb < 512; kb += 64) {
    #pragma unroll
    for (int s = 0; s < 4; ++s) {
      int slot = tid + s * 256;        // 1024 slots of 16 B
      int row = slot >> 3, seg = slot & 7;
      *(uint4*)(&As[row * 80 + seg * 8]) =
          *(const uint4*)(A + (size_t)(m0 + row) * lda + kb + seg * 8);
      *(uint4*)(&Bs[row * 80 + seg * 8]) =
          *(const uint4*)(B + (size_t)(n0 + row) * ldb + kb + seg * 8);
    }
    __syncthreads();
    #pragma unroll
    for (int kk = 0; kk < 2; ++kk) {
      bf16x8 af[4], bfr[4];
      #pragma unroll
      for (int i = 0; i < 4; ++i)
        af[i] = *(const bf16x8*)(&As[(wm + 16 * i + l16) * 80 + quad * 8 + kk * 32]);
      #pragma unroll
      for (int j = 0; j < 4; ++j)
        bfr[j] = *(const bf16x8*)(&Bs[(wn + 16 * j + l16) * 80 + quad * 8 + kk * 32]);
      #pragma unroll
      for (int i = 0; i < 4; ++i)
        #pragma unroll
        for (int j = 0; j < 4; ++j)
          acc[i][j] = __builtin_amdgcn_mfma_f32_16x16x32_bf16(af[i], bfr[j], acc[i][j], 0, 0, 0);
    }
    __syncthreads();
  }
  #pragma unroll
  for (int i = 0; i < 4; ++i)
    #pragma unroll
    for (int j = 0; j < 4; ++j)
      #pragma unroll
      for (int r = 0; r < 4; ++r) {
        int row = m0 + wm + 16 * i + quad * 4 + r;   // D row = M dim
        int col = n0 + wn + 16 * j + l16;            // D col = N dim
        float v = acc[i][j][r];
        if (MODE >= 1) v += bias[col];
        if (MODE == 0) {
          ((u16*)Cv)[(size_t)row * ldc + col] = f2bf(v);
        } else if (MODE == 1) {
          int bb = row >> 11, mm = row & 2047;
          int h = col >> 6, dd = col & 63;
          ((u16*)Cv)[(((size_t)(bb * NH + h)) * SEQL + mm) * HD + dd] = f2bf(v);
        } else {
          ((float*)Cv)[(size_t)row * ldc + col] = v;
        }
      }
}

// ---------------- causal flash attention, BM=BN=64, hd=64 ----------------
// Q/K/V: (BH=32, S=2048, 64) bf16.  O: (B, S, H*64) bf16.
__global__ __launch_bounds__(256) void flash_kernel(const u16* __restrict__ Q,
                                                    const u16* __restrict__ K,
                                                    const u16* __restrict__ V,
                                                    u16* __restrict__ O) {
  __shared__ u16 Ks[64 * 80];       // (kpos, hd) padded
  __shared__ u16 Vt[64 * 80];       // (hd, kpos) transposed, padded
  __shared__ u16 Ps[4 * 16 * 80];   // per-wave P tiles (16 rows x 64 keys)
  int tid = threadIdx.x;
  int wid = tid >> 6, lane = tid & 63, quad = lane >> 4, l16 = lane & 15;
  int bh = blockIdx.y;
  int b = bh >> 3, h = bh & 7;
  int q0 = blockIdx.x * 64;
  const u16* Qb = Q + (size_t)bh * SEQL * HD;
  const u16* Kb = K + (size_t)bh * SEQL * HD;
  const u16* Vb = V + (size_t)bh * SEQL * HD;

  // this wave's Q rows (16), A-fragments held in registers
  int qrow = q0 + wid * 16 + l16;
  bf16x8 qfrag0 = *(const bf16x8*)(Qb + (size_t)qrow * HD + quad * 8);
  bf16x8 qfrag1 = *(const bf16x8*)(Qb + (size_t)qrow * HD + quad * 8 + 32);

  f32x4 o_acc[4] = {};
  float m_i[4], l_i[4];
  #pragma unroll
  for (int r = 0; r < 4; ++r) { m_i[r] = -__builtin_inff(); l_i[r] = 0.f; }

  int nkb = q0 / 64 + 1;
  for (int kb = 0; kb < nkb; ++kb) {
    int k0 = kb * 64;
    // stage K tile + transposed V tile
    #pragma unroll
    for (int s = 0; s < 2; ++s) {
      int slot = tid + s * 256;          // 512 slots
      int row = slot >> 3, seg = slot & 7;
      uint4 kv = *(const uint4*)(Kb + (size_t)(k0 + row) * HD + seg * 8);
      *(uint4*)(&Ks[row * 80 + seg * 8]) = kv;
      union { uint4 v; u16 hx[8]; } tv;
      tv.v = *(const uint4*)(Vb + (size_t)(k0 + row) * HD + seg * 8);
      #pragma unroll
      for (int e = 0; e < 8; ++e) Vt[(seg * 8 + e) * 80 + row] = tv.hx[e];
    }
    __syncthreads();

    // S = Q @ K^T (this wave's 16 rows x 64 keys)
    f32x4 s_acc[4] = {};
    #pragma unroll
    for (int j = 0; j < 4; ++j) {
      bf16x8 bk0 = *(const bf16x8*)(&Ks[(j * 16 + l16) * 80 + quad * 8]);
      bf16x8 bk1 = *(const bf16x8*)(&Ks[(j * 16 + l16) * 80 + quad * 8 + 32]);
      s_acc[j] = __builtin_amdgcn_mfma_f32_16x16x32_bf16(qfrag0, bk0, s_acc[j], 0, 0, 0);
      s_acc[j] = __builtin_amdgcn_mfma_f32_16x16x32_bf16(qfrag1, bk1, s_acc[j], 0, 0, 0);
    }
    bool diag = (k0 == q0);
    #pragma unroll
    for (int j = 0; j < 4; ++j)
      #pragma unroll
      for (int r = 0; r < 4; ++r) {
        float sv = s_acc[j][r] * 0.125f;
        if (diag) {
          int keyl = j * 16 + l16;
          int rowl = wid * 16 + quad * 4 + r;
          if (keyl > rowl) sv = -__builtin_inff();
        }
        s_acc[j][r] = sv;
      }
    // online softmax (row stats replicated across the 16 lanes of a quad)
    float p[4][4], alpha[4];
    #pragma unroll
    for (int r = 0; r < 4; ++r) {
      float mx = fmaxf(fmaxf(s_acc[0][r], s_acc[1][r]), fmaxf(s_acc[2][r], s_acc[3][r]));
      #pragma unroll
      for (int off = 1; off < 16; off <<= 1) mx = fmaxf(mx, __shfl_xor(mx, off, 64));
      float m_new = fmaxf(m_i[r], mx);
      alpha[r] = __expf(m_i[r] - m_new);
      float rs = 0.f;
      #pragma unroll
      for (int j = 0; j < 4; ++j) { float pv = __expf(s_acc[j][r] - m_new); p[j][r] = pv; rs += pv; }
      #pragma unroll
      for (int off = 1; off < 16; off <<= 1) rs += __shfl_xor(rs, off, 64);
      l_i[r] = l_i[r] * alpha[r] + rs;
      m_i[r] = m_new;
    }
    #pragma unroll
    for (int j = 0; j < 4; ++j)
      #pragma unroll
      for (int r = 0; r < 4; ++r) o_acc[j][r] *= alpha[r];

    // P: C-layout -> LDS -> A-layout (per-wave region, in-order DS)
    u16* Pw = &Ps[wid * 16 * 80];
    #pragma unroll
    for (int j = 0; j < 4; ++j)
      #pragma unroll
      for (int r = 0; r < 4; ++r)
        Pw[(quad * 4 + r) * 80 + j * 16 + l16] = f2bf(p[j][r]);
    bf16x8 pf0 = *(const bf16x8*)(&Pw[l16 * 80 + quad * 8]);
    bf16x8 pf1 = *(const bf16x8*)(&Pw[l16 * 80 + quad * 8 + 32]);
    #pragma unroll
    for (int j = 0; j < 4; ++j) {
      bf16x8 bv0 = *(const bf16x8*)(&Vt[(j * 16 + l16) * 80 + quad * 8]);
      bf16x8 bv1 = *(const bf16x8*)(&Vt[(j * 16 + l16) * 80 + quad * 8 + 32]);
      o_acc[j] = __builtin_amdgcn_mfma_f32_16x16x32_bf16(pf0, bv0, o_acc[j], 0, 0, 0);
      o_acc[j] = __builtin_amdgcn_mfma_f32_16x16x32_bf16(pf1, bv1, o_acc[j], 0, 0, 0);
    }
    __syncthreads();
  }
  // write O in (b, m, h*64+dd) layout
  #pragma unroll
  for (int j = 0; j < 4; ++j)
    #pragma unroll
    for (int r = 0; r < 4; ++r) {
      int m = q0 + wid * 16 + quad * 4 + r;
      float v = o_acc[j][r] / l_i[r];
      O[((size_t)(b * SEQL + m)) * 512 + h * HD + j * 16 + l16] = f2bf(v);
    }
}

extern "C" void kernel_launch(void* const* d_in, const int* in_sizes, int n_in,
                              void* d_out, int out_size, void* d_ws, size_t ws_size,
                              hipStream_t stream) {
  const float* x   = (const float*)d_in[0];
  const float* Wq  = (const float*)d_in[1];
  const float* Wk  = (const float*)d_in[2];
  const float* Wv  = (const float*)d_in[3];
  // d_in[4] = R (2 GiB) -- never read; rotation recomputed analytically
  const float* ipw = (const float*)d_in[5];
  const float* ipb = (const float*)d_in[6];
  const float* ow  = (const float*)d_in[7];
  const float* ob  = (const float*)d_in[8];
  float* out = (float*)d_out;

  char* w = (char*)d_ws;
  auto alloc = [&](size_t bytes) { void* p = w; w += bytes; return p; };
  u16* xb    = (u16*)alloc(8192UL * 512 * 2);
  u16* Wcatb = (u16*)alloc(3UL * 512 * 512 * 2);   // Wq|Wk|Wv contiguous
  u16* ipwb  = (u16*)alloc(1536UL * 512 * 2);
  u16* owb   = (u16*)alloc(512UL * 512 * 2);
  u16* QKV0  = (u16*)alloc(8192UL * 1536 * 2);     // fused q|k|v, roped in place
  u16* qp    = (u16*)alloc(8192UL * 512 * 2);      // (bh, m, hd)
  u16* kp    = (u16*)alloc(8192UL * 512 * 2);
  u16* vp    = (u16*)alloc(8192UL * 512 * 2);
  u16* Ob    = (u16*)alloc(8192UL * 512 * 2);      // (b, m, h*hd)
  float2* T  = (float2*)alloc(2048UL * 256 * sizeof(float2));

  rot_table_kernel<<<2048, 256, 0, stream>>>(T);
  cvt_kernel<<<4194304 / 1024, 256, 0, stream>>>(x, xb, 4194304);
  cvt_kernel<<<262144 / 1024, 256, 0, stream>>>(Wq, Wcatb, 262144);
  cvt_kernel<<<262144 / 1024, 256, 0, stream>>>(Wk, Wcatb + 262144, 262144);
  cvt_kernel<<<262144 / 1024, 256, 0, stream>>>(Wv, Wcatb + 524288, 262144);
  cvt_kernel<<<786432 / 1024, 256, 0, stream>>>(ipw, ipwb, 786432);
  cvt_kernel<<<262144 / 1024, 256, 0, stream>>>(ow, owb, 262144);

  // QKV0 = x @ [Wq;Wk;Wv]^T   (M=8192, N=1536, K=512)
  gemm_bt<0><<<dim3(12, 64), 256, 0, stream>>>(xb, 512, Wcatb, 512, nullptr, QKV0, 1536);
  // rope (in place)
  rope_kernel<<<8192, 256, 0, stream>>>(QKV0, T);
  // in_proj (+bias), head-reordered outputs
  gemm_bt<1><<<dim3(4, 64), 256, 0, stream>>>(QKV0,        1536, ipwb,               512, ipb,        qp, 0);
  gemm_bt<1><<<dim3(4, 64), 256, 0, stream>>>(QKV0 + 512,  1536, ipwb + 512 * 512,   512, ipb + 512,  kp, 0);
  gemm_bt<1><<<dim3(4, 64), 256, 0, stream>>>(QKV0 + 1024, 1536, ipwb + 1024 * 512,  512, ipb + 1024, vp, 0);
  // causal flash attention
  flash_kernel<<<dim3(32, 32), 256, 0, stream>>>(qp, kp, vp, Ob);
  // out projection (+bias) -> fp32 d_out
  gemm_bt<2><<<dim3(4, 64), 256, 0, stream>>>(Ob, 512, owb, 512, ob, out, 512);
}